// Round 1
// baseline (305.208 us; speedup 1.0000x reference)
//
#include <hip/hip_runtime.h>

// SoftmaxCascade: B=8192 rows, E=4681 nodes, 8-ary implicit heap
// (children of p = 8p+1..8p+8). out[0]=1; out[i]=exp(x[i]+D[(i-1)>>3]) where
// D[g]=adj[g]+x[g]+D[parent(g)], D[0]=adj[0], adj[g]=-m-log(sum exp(x_c-m)).
//
// R3 post-mortem: VGPR_Count=24 proves the compiler serialized/remat'd the
// "register-resident" loads (27 floats cannot live in 24 regs across two
// barriers) -> latency-bound, all pipes idle (VALU 19%, HBM 31%).
// R4: (a) sched_barrier(0) pins ALL loads before compute (forces wide issue,
// ~50 VGPR, launch_bounds(256,8) keeps 8 blocks/CU); (b) ownership shift:
// thread g writes out[8g+1..8g+8] which all use its OWN D[g] -> dj[] array,
// second barrier, and neighbor dependency deleted; (c) ancestor x values
// loaded from global (L1-hot broadcast gathers) in the load phase -> xn[]
// staging deleted. One barrier, LDS = adj[585] only (2.3 KB).

constexpr int E  = 4681;
constexpr int NG = 585;                 // internal nodes / sibling groups

// Load the 8 children of group g: nodes 8g+1..8g+8, element 8g+1+t == L[S+t].
// S = (rowbase+1)&3: rin + 8g+1-S is 16B-aligned. Two aligned float4 (plus a
// third when S!=0) cover [8g+1-S, 8g+1-S+11]; max index 8*583+12 = 4676 < E.
// g==584 (tail) takes the scalar path: its window ends exactly at E-1=4680,
// but the vector window would read up to 3 floats past the (page-aligned)
// buffer end on the last row.
template<int S>
__device__ __forceinline__ void loadL(const float* __restrict__ rin, int g, float L[12]) {
    if (g == 584) {
        #pragma unroll
        for (int t = 0; t < 8; ++t) L[S + t] = rin[4673 + t];
        return;
    }
    const float* ap = rin + 8 * g + 1 - S;          // 16B-aligned
    const float4 A = *(const float4*)ap;
    const float4 B = *(const float4*)(ap + 4);
    L[0] = A.x; L[1] = A.y; L[2] = A.z; L[3] = A.w;
    L[4] = B.x; L[5] = B.y; L[6] = B.z; L[7] = B.w;
    if (S != 0) {                                    // S==0: 8 floats exact, no 3rd load
        const float4 C = *(const float4*)(ap + 8);
        L[8] = C.x; L[9] = C.y; L[10] = C.z; L[11] = C.w;
    }
}

template<int S>
__device__ __forceinline__ float group_adj(const float L[12]) {
    float m = L[S];
    #pragma unroll
    for (int t = 1; t < 8; ++t) m = fmaxf(m, L[S + t]);
    float s = 0.0f;
    #pragma unroll
    for (int t = 0; t < 8; ++t) s += __expf(L[S + t] - m);
    return -m - __logf(s);
}

// Store exp(L[S+t]+D) -> q[t], t=0..7, q = rout + 8g+1 (float index == S mod 4).
template<int S>
__device__ __forceinline__ void store8(float* __restrict__ q, const float L[12], float D) {
    float y[8];
    #pragma unroll
    for (int t = 0; t < 8; ++t) y[t] = __expf(L[S + t] + D);
    if (S == 0) {
        *(float4*)(q)     = make_float4(y[0], y[1], y[2], y[3]);
        *(float4*)(q + 4) = make_float4(y[4], y[5], y[6], y[7]);
    } else if (S == 1) {
        q[0] = y[0];
        *(float2*)(q + 1) = make_float2(y[1], y[2]);
        *(float4*)(q + 3) = make_float4(y[3], y[4], y[5], y[6]);
        q[7] = y[7];
    } else if (S == 2) {
        *(float2*)(q)     = make_float2(y[0], y[1]);
        *(float4*)(q + 2) = make_float4(y[2], y[3], y[4], y[5]);
        *(float2*)(q + 6) = make_float2(y[6], y[7]);
    } else {
        q[0] = y[0];
        *(float4*)(q + 1) = make_float4(y[1], y[2], y[3], y[4]);
        *(float2*)(q + 5) = make_float2(y[5], y[6]);
        q[7] = y[7];
    }
}

template<int S>
__device__ __forceinline__ void row_body(const float* __restrict__ rin,
                                         float* __restrict__ rout,
                                         float* adj, int tid) {
    const int g0 = tid, g1 = tid + 256, g2 = tid + 512;   // g0,g1 always valid
    const bool h2 = (g2 < NG);                             // tid < 73

    // ---------- phase A: issue ALL global loads ----------
    float L0[12], L1[12], L2[12];
    loadL<S>(rin, g0, L0);
    loadL<S>(rin, g1, L1);

    // ancestor x gathers (addresses are pure functions of tid; 8-lane broadcast)
    const int p0   = (g0 - 1) >> 3;
    const int pc0  = p0 < 0 ? 0 : p0;
    const int pp0  = (pc0 - 1) >> 3;
    const int ppc0 = pp0 < 0 ? 0 : pp0;
    const float xg0 = rin[g0], xp0 = rin[pc0], xpp0 = rin[ppc0];

    const int p1 = (g1 - 1) >> 3, pp1 = (p1 - 1) >> 3;     // depth-3: p1,pp1 > 0
    const float xg1 = rin[g1], xp1 = rin[p1], xpp1 = rin[pp1];

    int p2 = 0, pp2 = 0;
    float xg2 = 0.f, xp2 = 0.f, xpp2 = 0.f;
    if (h2) {
        loadL<S>(rin, g2, L2);
        p2 = (g2 - 1) >> 3; pp2 = (p2 - 1) >> 3;           // depth-3: p2,pp2 > 0
        xg2 = rin[g2]; xp2 = rin[p2]; xpp2 = rin[pp2];
    }
    __builtin_amdgcn_sched_barrier(0);   // pin: no compute may be hoisted above,
                                         // no load may be sunk below (defeats the
                                         // pressure-minimizing re-serialization)

    // ---------- phase B: per-group softmax adjustment ----------
    const float adj0 = group_adj<S>(L0);
    const float adj1 = group_adj<S>(L1);
    adj[g0] = adj0;
    adj[g1] = adj1;
    float adj2 = 0.f;
    if (h2) { adj2 = group_adj<S>(L2); adj[g2] = adj2; }
    __syncthreads();                     // the only barrier

    // ---------- phase C: walk ancestors, exponentiate, store ----------
    const float a00 = adj[0];
    const float a10 = adj[pc0], a20 = adj[ppc0];
    float D0 = adj0;                     // level-guarded accumulation for g0
    if (g0 > 0) {
        D0 += xg0 + a10;
        if (p0 > 0) {
            D0 += xp0 + a20;
            if (pp0 > 0) D0 += xpp0 + a00;
        }
    }
    const float D1 = adj1 + xg1 + adj[p1] + xp1 + adj[pp1] + xpp1 + a00;

    store8<S>(rout + 8 * g0 + 1, L0, D0);
    store8<S>(rout + 8 * g1 + 1, L1, D1);
    if (h2) {
        const float D2 = adj2 + xg2 + adj[p2] + xp2 + adj[pp2] + xpp2 + a00;
        store8<S>(rout + 8 * g2 + 1, L2, D2);
    }
    if (tid == 0) rout[0] = 1.0f;        // root probability
}

__global__ __launch_bounds__(256, 8) void cascade_kernel(const float* __restrict__ in,
                                                         float* __restrict__ out) {
    __shared__ float adj[NG];            // 2.3 KB; only LDS left
    const int tid = threadIdx.x;
    const long long rowbase = (long long)blockIdx.x * (long long)E;
    const float* rin = in + rowbase;
    float* rout = out + rowbase;
    switch ((int)((rowbase + 1) & 3)) {  // store/window remainder; block-uniform
        case 0: row_body<0>(rin, rout, adj, tid); break;
        case 1: row_body<1>(rin, rout, adj, tid); break;
        case 2: row_body<2>(rin, rout, adj, tid); break;
        case 3: row_body<3>(rin, rout, adj, tid); break;
    }
}

extern "C" void kernel_launch(void* const* d_in, const int* in_sizes, int n_in,
                              void* d_out, int out_size, void* d_ws, size_t ws_size,
                              hipStream_t stream) {
    const float* in = (const float*)d_in[0];   // [B, E] float32
    float* out = (float*)d_out;                // [B, E] float32
    const int B = in_sizes[0] / E;             // 8192
    cascade_kernel<<<B, 256, 0, stream>>>(in, out);
}

// Round 2
// 297.193 us; speedup vs baseline: 1.0270x; 1.0270x over previous
//
#include <hip/hip_runtime.h>

// SoftmaxCascade: B=8192 rows, E=4681 nodes, 8-ary implicit heap
// (children of p = 8p+1..8p+8). out[0]=1; out[i]=exp(x[i]+D[(i-1)>>3]) where
// D[g]=adj[g]+x[g]+D[parent(g)], D[0]=adj[0], adj[g]=-m-log(sum exp(x_c-m)).
//
// R4 post-mortem: VGPR=32 < ~40 live floats => compiler re-loads from global
// after the barrier; sched_barrier can't stop within-region serialization.
// Latency-bound, all pipes idle (VALU 16%, HBM 36%).
// R5: global_load_lds DMA staging (zero VGPR results, cannot be serialized)
// with m173 pre-swizzled GLOBAL addresses -> pad-9 LDS layout:
//   xs[slot(i)] = x[i],  slot(i) = 9*(i>>3) + (i&7)
// Window of group g = slots {9g+1..9g+7, 9g+9}: lane stride 9 dwords = 2-way
// bank aliasing = free (m136). Pad slots 9g+8 store adj[g] (no extra array).
// Input read from HBM exactly once; all loads dword-aligned (S only for stores).

constexpr int E     = 4681;
constexpr int NG    = 585;              // sibling groups (internal nodes)
constexpr int NSLOT = 5266;             // max slot = slot(4680) = 5265

__device__ __forceinline__ int xslot(int i) { return 9 * (i >> 3) + (i & 7); }

__device__ __forceinline__ void async_ld(const float* g, float* l) {
    __builtin_amdgcn_global_load_lds(
        (const __attribute__((address_space(1))) void*)g,
        (__attribute__((address_space(3))) void*)l, 4, 0, 0);
}

__device__ __forceinline__ float group_adj(const float w[8]) {
    float m = w[0];
    #pragma unroll
    for (int k = 1; k < 8; ++k) m = fmaxf(m, w[k]);
    float s = 0.0f;
    #pragma unroll
    for (int k = 0; k < 8; ++k) s += __expf(w[k] - m);
    return -m - __logf(s);
}

__device__ __forceinline__ void rdwin(const float* xs, int g, float w[8]) {
    const float* b = xs + 9 * g;        // nodes 8g+1..8g+8 at b[1..7], b[9]
    #pragma unroll
    for (int k = 0; k < 7; ++k) w[k] = b[1 + k];
    w[7] = b[9];
}

// D(g) = adj(g) + sum over ancestors a of (x(a) + adj(parent(a))), depth<=3.
__device__ __forceinline__ float walkD(const float* xs, int g, float adjv) {
    float D = adjv;
    if (g > 0) {
        const int p = (g - 1) >> 3;
        D += xs[xslot(g)] + xs[9 * p + 8];            // x(g) + adj(p)
        if (p > 0) {
            const int pp = (p - 1) >> 3;
            D += xs[xslot(p)] + xs[9 * pp + 8];       // x(p) + adj(pp)
            if (pp > 0) D += xs[xslot(pp)] + xs[8];   // x(pp) + adj(root grp)
        }
    }
    return D;
}

// Store exp(x[8g+1+t]+D) -> rout[8g+1+t], t=0..7. Global float index of
// rout+8g+1 is rowbase+8g+1 === S (mod 4): natural-alignment segments.
template<int S>
__device__ __forceinline__ void emit(float* __restrict__ rout, const float* xs,
                                     int g, float D) {
    float y[8];
    {
        const float* b = xs + 9 * g;
        #pragma unroll
        for (int k = 0; k < 7; ++k) y[k] = __expf(b[1 + k] + D);
        y[7] = __expf(b[9] + D);
    }
    float* q = rout + 8 * g + 1;
    if (S == 0) {
        *(float4*)(q)     = make_float4(y[0], y[1], y[2], y[3]);
        *(float4*)(q + 4) = make_float4(y[4], y[5], y[6], y[7]);
    } else if (S == 1) {
        q[0] = y[0];
        *(float2*)(q + 1) = make_float2(y[1], y[2]);
        *(float4*)(q + 3) = make_float4(y[3], y[4], y[5], y[6]);
        q[7] = y[7];
    } else if (S == 2) {
        *(float2*)(q)     = make_float2(y[0], y[1]);
        *(float4*)(q + 2) = make_float4(y[2], y[3], y[4], y[5]);
        *(float2*)(q + 6) = make_float2(y[6], y[7]);
    } else {
        q[0] = y[0];
        *(float4*)(q + 1) = make_float4(y[1], y[2], y[3], y[4]);
        *(float2*)(q + 5) = make_float2(y[5], y[6]);
        q[7] = y[7];
    }
}

template<int S>
__device__ __forceinline__ void row_body(const float* __restrict__ rin,
                                         float* __restrict__ rout,
                                         float* xs, int tid) {
    // ---------- phase A: DMA row -> LDS (permuted), fire-and-forget ----------
    // Slot s (s%9 != 8) holds node 8*(s/9) + s%9; consecutive active slots map
    // to consecutive global floats -> fully coalesced per-lane dword loads.
    const int lbase = tid & ~63;                       // wave-uniform LDS base
    #pragma unroll
    for (int j = 0; j < 21; ++j) {                     // 21*256 = 5376 >= NSLOT
        const int s = 256 * j + tid;
        if (s < NSLOT && (s % 9) != 8) {
            async_ld(rin + 8 * (s / 9) + (s % 9), xs + 256 * j + lbase);
        }
    }
    asm volatile("s_waitcnt vmcnt(0)" ::: "memory");
    __syncthreads();

    // ---------- phase B: per-group softmax adj -> pad slots ----------
    const int g0 = tid, g1 = tid + 256, g2 = tid + 512;
    const bool h2 = (g2 < NG);                         // tid < 73
    float w[8];
    rdwin(xs, g0, w);
    const float a0 = group_adj(w);
    rdwin(xs, g1, w);
    const float a1 = group_adj(w);
    float a2 = 0.f;
    if (h2) { rdwin(xs, g2, w); a2 = group_adj(w); }
    xs[9 * g0 + 8] = a0;                               // pad slots: disjoint from
    xs[9 * g1 + 8] = a1;                               // all window reads -> no race
    if (h2) xs[9 * g2 + 8] = a2;
    __syncthreads();

    // ---------- phase C: ancestor walk + exp + segmented stores ----------
    emit<S>(rout, xs, g0, walkD(xs, g0, a0));
    emit<S>(rout, xs, g1, walkD(xs, g1, a1));
    if (h2) emit<S>(rout, xs, g2, walkD(xs, g2, a2));
    if (tid == 0) rout[0] = 1.0f;                      // root probability
}

__global__ __launch_bounds__(256, 7) void cascade_kernel(const float* __restrict__ in,
                                                         float* __restrict__ out) {
    __shared__ float xs[NSLOT];                        // 21.1 KB -> 7 blocks/CU
    const int tid = threadIdx.x;
    const long long rowbase = (long long)blockIdx.x * (long long)E;
    const float* rin = in + rowbase;
    float* rout = out + rowbase;
    switch ((int)((rowbase + 1) & 3)) {                // block-uniform store phase
        case 0: row_body<0>(rin, rout, xs, tid); break;
        case 1: row_body<1>(rin, rout, xs, tid); break;
        case 2: row_body<2>(rin, rout, xs, tid); break;
        case 3: row_body<3>(rin, rout, xs, tid); break;
    }
}

extern "C" void kernel_launch(void* const* d_in, const int* in_sizes, int n_in,
                              void* d_out, int out_size, void* d_ws, size_t ws_size,
                              hipStream_t stream) {
    const float* in = (const float*)d_in[0];   // [B, E] float32
    float* out = (float*)d_out;                // [B, E] float32
    const int B = in_sizes[0] / E;             // 8192
    cascade_kernel<<<B, 256, 0, stream>>>(in, out);
}